// Round 10
// baseline (380.037 us; speedup 1.0000x reference)
//
#include <hip/hip_runtime.h>

#define NN 25000
#define NE 400000
#define CH 128
#define ECH 64
#define KTOT 320          // 2*CH + ECH
#define BE 64             // edges per tile
#define NTILE (NE / BE)   // 6250

typedef _Float16 half8 __attribute__((ext_vector_type(8)));
typedef _Float16 half4v __attribute__((ext_vector_type(4)));
typedef float f32x4 __attribute__((ext_vector_type(4)));
typedef unsigned int u32;

__device__ __forceinline__ void gload16(const void* gsrc, void* ldsdst) {
    __builtin_amdgcn_global_load_lds((const __attribute__((address_space(1))) u32*)gsrc,
                                     (__attribute__((address_space(3))) u32*)ldsdst,
                                     16, 0, 0);
}

// ---- k1: out=x copy, xh=fp16(x), pack W, histogram (cnt pre-zeroed by memset) ----
__global__ __launch_bounds__(256) void prep_hist_kernel(
    const float* __restrict__ x, const int* __restrict__ eidx,
    const float* __restrict__ gw, const float* __restrict__ mw,
    float* __restrict__ out, _Float16* __restrict__ xh, _Float16* __restrict__ wp,
    int* __restrict__ cnt)
{
    const int gtid = blockIdx.x * 256 + threadIdx.x;
    const int gsz  = gridDim.x * 256;

    for (int i = gtid; i < (NN * CH) / 4; i += gsz) {     // 800000 float4 units
        float4 v = ((const float4*)x)[i];
        ((float4*)out)[i] = v;
        half4v h;
        h[0] = (_Float16)v.x; h[1] = (_Float16)v.y;
        h[2] = (_Float16)v.z; h[3] = (_Float16)v.w;
        ((half4v*)xh)[i] = h;
    }
    for (int t = gtid; t < 81920; t += gsz) {             // W -> MFMA B-fragment order
        int i    = t & 7;
        int lane = (t >> 3) & 63;
        int ks   = (t >> 9) % 10;
        int gct  = t / 5120;          // 0..15
        int w  = gct >> 2, ct = gct & 3;
        int ch = w * 32 + (ct & 1) * 16 + (lane & 15);
        int k  = ks * 32 + 8 * (lane >> 4) + i;
        const float* src = (ct < 2) ? gw : mw;
        wp[t] = (_Float16)src[ch * KTOT + k];
    }
    for (int i = gtid; i < NE; i += gsz) atomicAdd(&cnt[eidx[NE + i]], 1);
}

// ---- k2: exclusive scan of 25000 counts, one block, shuffle-based ----
__global__ __launch_bounds__(1024) void scan_kernel(const int* __restrict__ cnt,
                                                    int* __restrict__ offs) {
    __shared__ int wsum[16];
    const int tid  = threadIdx.x;
    const int lane = tid & 63;
    const int wv   = tid >> 6;

    int vals[25];
    int s = 0;
    if (tid < 1000) {
        #pragma unroll
        for (int j = 0; j < 25; ++j) { vals[j] = cnt[tid * 25 + j]; s += vals[j]; }
    }
    // inclusive wave scan of s
    int ps = s;
    #pragma unroll
    for (int off = 1; off < 64; off <<= 1) {
        int t = __shfl_up(ps, off);
        if (lane >= off) ps += t;
    }
    if (lane == 63) wsum[wv] = ps;
    __syncthreads();
    if (wv == 0 && lane < 16) {
        int v = wsum[lane];
        int pv = v;
        #pragma unroll
        for (int off = 1; off < 16; off <<= 1) {
            int t = __shfl_up(pv, off);
            if (lane >= off) pv += t;
        }
        wsum[lane] = pv - v;            // exclusive wave base
    }
    __syncthreads();
    if (tid < 1000) {
        int base = wsum[wv] + ps - s;   // global exclusive prefix for this thread
        #pragma unroll
        for (int j = 0; j < 25; ++j) { offs[tid * 25 + j] = base; base += vals[j]; }
    }
}

// ---- k3: rank edges into perm; offs consumed destructively ----
__global__ __launch_bounds__(256) void rank_kernel(
    const int* __restrict__ eidx, int* __restrict__ offs, int* __restrict__ perm)
{
    const int gtid = blockIdx.x * 256 + threadIdx.x;
    const int gsz  = gridDim.x * 256;
    for (int i = gtid; i < NE; i += gsz) {
        int c = eidx[NE + i];
        int p = atomicAdd(&offs[c], 1);
        perm[p] = i;
    }
}

// ---- k4: main fused edge GEMM + activations + segmented scatter ----
// Phase A (K 0..255 = x[row]|x[col]): global_load_lds, pre-swizzled source,
//   swizzled ds_read (both-sides swizzle, proven R7).
// Phase B (K 256..319 = eattr): per-lane direct loads -> f16 A-fragments in
//   REGISTERS (no LDS, no extra barriers); 4x wave redundancy is L1-absorbed.
__global__ __launch_bounds__(256, 4) void cgconv_kernel(
    const _Float16* __restrict__ xh,
    const float* __restrict__ eattr,
    const _Float16* __restrict__ wp,
    const int* __restrict__ eidx,
    const int* __restrict__ perm,
    const float* __restrict__ gate_b,
    const float* __restrict__ msg_b,
    float* __restrict__ out)
{
    __shared__ __align__(16) char smem[BE * 256 * 2];   // 32 KB: Z[64][256]f16 / M[64][128]f32
    __shared__ int rowI[BE];
    __shared__ int colI[BE];
    __shared__ int sI[BE];

    const int tid = threadIdx.x;
    const int e0  = blockIdx.x * BE;    // identity tile order (col-sorted => write locality)

    if (tid < BE) {
        int p = perm[e0 + tid];
        sI[tid]   = p;
        rowI[tid] = eidx[p];
        colI[tid] = eidx[NE + p];
    }
    __syncthreads();

    const int lane = tid & 63;
    const int w    = tid >> 6;          // wave: channels [32w, 32w+32)
    const int l15  = lane & 15;
    const int lg   = lane >> 4;
    const int wvs  = tid & ~63;

    // ---- phase A staging: 2048 16B chunks via global_load_lds, swizzled source ----
    #pragma unroll
    for (int it = 0; it < 8; ++it) {
        int s  = it * 256 + wvs + lane;
        int e  = s >> 5, cs = s & 31;
        int cp = cs ^ (e & 7);                    // xor low 3 bits of chunk id
        int rr = (cs < 16) ? rowI[e] : colI[e];
        const _Float16* src = xh + (size_t)rr * CH + (cp & 15) * 8;
        gload16(src, (char*)smem + (size_t)(it * 256 + wvs) * 16);
    }

    // ---- phase B: eattr -> A-fragments in registers (overlaps staging latency) ----
    half8 pa[4][2];                     // [rt][ks-8]
    #pragma unroll
    for (int rt = 0; rt < 4; ++rt) {
        int e = sI[rt * 16 + l15];
        const f32x4* ep = (const f32x4*)&eattr[(size_t)e * ECH + lg * 8];
        f32x4 v0 = ep[0], v1 = ep[1];   // k = 256 + 8lg .. +8  (ks=8)
        f32x4 w0 = ep[8], w1 = ep[9];   // k = 288 + 8lg .. +8  (ks=9)
        half8 h0, h1;
        #pragma unroll
        for (int j = 0; j < 4; ++j) {
            h0[j]     = (_Float16)v0[j];
            h0[j + 4] = (_Float16)v1[j];
            h1[j]     = (_Float16)w0[j];
            h1[j + 4] = (_Float16)w1[j];
        }
        pa[rt][0] = h0;
        pa[rt][1] = h1;
    }
    __syncthreads();   // drains vmcnt: Z ready

    f32x4 acc[4][4];
    #pragma unroll
    for (int rt = 0; rt < 4; ++rt)
        #pragma unroll
        for (int ct = 0; ct < 4; ++ct) {
            acc[rt][ct][0] = 0.f; acc[rt][ct][1] = 0.f;
            acc[rt][ct][2] = 0.f; acc[rt][ct][3] = 0.f;
        }

    const half8* wpf = (const half8*)wp;

    // ---- MFMA phase A (ks 0..7), swizzled LDS reads ----
    #pragma unroll
    for (int ks = 0; ks < 8; ++ks) {
        half8 a[4], b[4];
        #pragma unroll
        for (int rt = 0; rt < 4; ++rt) {
            int R = rt * 16 + l15;
            int slot = (ks * 4 + lg) ^ (l15 & 7);
            a[rt] = *(const half8*)((const char*)smem + (size_t)R * 512 + slot * 16);
        }
        #pragma unroll
        for (int ct = 0; ct < 4; ++ct)
            b[ct] = wpf[(((w * 4 + ct) * 10) + ks) * 64 + lane];
        #pragma unroll
        for (int rt = 0; rt < 4; ++rt)
            #pragma unroll
            for (int ct = 0; ct < 4; ++ct)
                acc[rt][ct] = __builtin_amdgcn_mfma_f32_16x16x32_f16(a[rt], b[ct], acc[rt][ct], 0, 0, 0);
    }

    // ---- MFMA phase B (ks 8..9) from registers ----
    #pragma unroll
    for (int ks2 = 0; ks2 < 2; ++ks2) {
        half8 b[4];
        #pragma unroll
        for (int ct = 0; ct < 4; ++ct)
            b[ct] = wpf[(((w * 4 + ct) * 10) + 8 + ks2) * 64 + lane];
        #pragma unroll
        for (int rt = 0; rt < 4; ++rt)
            #pragma unroll
            for (int ct = 0; ct < 4; ++ct)
                acc[rt][ct] = __builtin_amdgcn_mfma_f32_16x16x32_f16(pa[rt][ks2], b[ct], acc[rt][ct], 0, 0, 0);
    }
    __syncthreads();   // all Z reads done; smem reused as M

    // ---- activations -> M[le][ch] (XOR-swizzled across lg groups) ----
    float* M = (float*)smem;
    #pragma unroll
    for (int ct = 0; ct < 2; ++ct) {
        int ch  = w * 32 + ct * 16 + l15;
        int chs = ch ^ (lg << 3);
        float gb = gate_b[ch];
        float mb = msg_b[ch];
        #pragma unroll
        for (int rt = 0; rt < 4; ++rt) {
            #pragma unroll
            for (int rg = 0; rg < 4; ++rg) {
                int le = rt * 16 + lg * 4 + rg;    // C layout: row = 4*lg + reg
                float gv = acc[rt][ct][rg] + gb;
                float mv = acc[rt][ct + 2][rg] + mb;
                float g  = __builtin_amdgcn_rcpf(1.0f + __expf(-gv));
                float sp = (mv > 15.0f) ? mv : __logf(1.0f + __expf(mv));
                M[le * CH + chs] = g * sp;
            }
        }
    }
    __syncthreads();

    // ---- segmented walk over sorted cols: one atomic per (distinct col, channel) ----
    int ch2 = tid & 127;
    int h   = tid >> 7;
    float a2 = 0.f;
    int prev = colI[h * 32];
    for (int i2 = 0; i2 < 32; ++i2) {
        int e = h * 32 + i2;
        int c = colI[e];
        float m = M[e * CH + (ch2 ^ (((e >> 2) & 3) << 3))];
        if (c != prev) {
            atomicAdd(&out[(size_t)prev * CH + ch2], a2);
            a2 = 0.f;
            prev = c;
        }
        a2 += m;
    }
    atomicAdd(&out[(size_t)prev * CH + ch2], a2);
}

extern "C" void kernel_launch(void* const* d_in, const int* in_sizes, int n_in,
                              void* d_out, int out_size, void* d_ws, size_t ws_size,
                              hipStream_t stream) {
    const float* x      = (const float*)d_in[0];
    const int*   eidx   = (const int*)d_in[1];
    const float* eattr  = (const float*)d_in[2];
    const float* gate_w = (const float*)d_in[3];
    const float* gate_b = (const float*)d_in[4];
    const float* msg_w  = (const float*)d_in[5];
    const float* msg_b  = (const float*)d_in[6];
    float* outp = (float*)d_out;

    char* ws = (char*)d_ws;
    _Float16* xh  = (_Float16*)(ws);                 // 6,400,000 B
    _Float16* wp  = (_Float16*)(ws + 6400000);       //   163,840 B
    int* cnt  = (int*)(ws + 6563840);                //   100,096 B
    int* offs = (int*)(ws + 6663936);                //   100,096 B
    int* perm = (int*)(ws + 6764032);                // 1,600,000 B (ends 8,364,032)

    hipMemsetAsync(cnt, 0, 100096, stream);
    prep_hist_kernel<<<2048, 256, 0, stream>>>(x, eidx, gate_w, msg_w, outp, xh, wp, cnt);
    scan_kernel<<<1, 1024, 0, stream>>>(cnt, offs);
    rank_kernel<<<1024, 256, 0, stream>>>(eidx, offs, perm);
    cgconv_kernel<<<NTILE, 256, 0, stream>>>(xh, eattr, wp, eidx, perm, gate_b, msg_b, outp);
}